// Round 4
// baseline (450.871 us; speedup 1.0000x reference)
//
#include <hip/hip_runtime.h>
#include <hip/hip_bf16.h>

#define ND 100000
#define NG 50000
#define NF 128
#define NE 600000
#define NTOT 300000          // packed dst rows  [dd(100k) | gd(100k) | dg(50k) | gg(50k)]
#define ETOT 2400000         // 4*NE
#define XD_ELEMS 12800000    // ND*NF
#define XTOT 19200000        // (ND+NG)*NF
#define CB 9375              // XTOT/2048 blocks (convert role)
#define PB 256               // weight-prep role blocks
#define HB 256               // histogram role blocks (= edge slices)
#define EPS 9375             // edges per slice (64 slices per etype)
#define NBKT 1172            // ceil(300032/256): dst/src buckets of 256 ids
#define BSH 8                // bucket = id >> 8
#define CAP 8192             // passCd LDS stage capacity (max bucket ~3350)
#define SAB 19               // scanA blocks per table = ceil(NBKT/64)
#define G0 1563              // ceil(ND/64) fused-kernel drug blocks
#define G1 782               // ceil(NG/64) fused-kernel gene blocks
#define ALD 260              // A-stage LDS row stride (bf16 elems): 520 B -> conflict-free

typedef __hip_bfloat16 bf16;
typedef __attribute__((ext_vector_type(8))) short bf16x8;
typedef __attribute__((ext_vector_type(4))) float f32x4;

// ---------------------------------------------------------------------------
// Dtype detector: fp32 data read as bf16 halfwords shows huge exponents in the
// mantissa-low halves; genuine bf16 N(0,1) never does. flag=1 -> fp32 inputs.
// ---------------------------------------------------------------------------
__global__ void detect_kernel(const void* __restrict__ x, int* __restrict__ flag)
{
    const unsigned short* u = (const unsigned short*)x;
    int l = threadIdx.x;  // 64 threads
    int found = 0;
    for (int i = 0; i < 64; ++i) {
        unsigned short v = u[l * 64 + i];
        int e = (v >> 7) & 0xFF;
        if (e >= 137) found = 1;
    }
    int any = __any(found);
    if (l == 0) *flag = any ? 1 : 0;
}

// ---------------------------------------------------------------------------
// Etype select helper: slice blk in [0,256), 64 slices per etype.
// ---------------------------------------------------------------------------
#define ETYPE_SELECT(blk)                                                     \
    const int e_ = (blk) >> 6;                                                \
    const int lo_ = ((blk) & 63) * EPS;                                       \
    const int *sp_, *dp_; int sbase_, dbase_;                                 \
    if (e_ == 0)      { sp_ = src_dd; dp_ = dst_dd; sbase_ = 0;         dbase_ = 0; }          \
    else if (e_ == 1) { sp_ = src_gd; dp_ = dst_gd; sbase_ = ND;        dbase_ = ND; }         \
    else if (e_ == 2) { sp_ = src_dg; dp_ = dst_dg; sbase_ = ND + NG;   dbase_ = 2 * ND; }     \
    else              { sp_ = src_gg; dp_ = dst_gg; sbase_ = 2*ND+NG;   dbase_ = 2*ND + NG; }

// ---------------------------------------------------------------------------
// Fused pre-pass (NO global atomics anywhere), three block-ranges:
//   [0,HB)        PassA: per-slice LDS histograms over 1172 coarse buckets
//   [HB,HB+CB)    x fp32 -> bf16 conversion (skipped if bf16 input)
//   [+PB)         MFMA-swizzled B prep: Bsw[2][256k][128n], n column-permuted
//                 (slot (nt,q) holds col q*8+nt) -> contiguous epilogue stores
// ---------------------------------------------------------------------------
__global__ __launch_bounds__(256) void pre_kernel(
    const int* __restrict__ src_dd, const int* __restrict__ dst_dd,
    const int* __restrict__ src_gd, const int* __restrict__ dst_gd,
    const int* __restrict__ src_dg, const int* __restrict__ dst_dg,
    const int* __restrict__ src_gg, const int* __restrict__ dst_gg,
    int* __restrict__ tabD, int* __restrict__ tabS,   // [HB][NBKT]
    const void* __restrict__ x_drug, const void* __restrict__ x_gene,
    bf16* __restrict__ conv,
    const void* __restrict__ W_dd, const void* __restrict__ W_gd,
    const void* __restrict__ W_dg, const void* __restrict__ W_gg,
    bf16* __restrict__ Bsw, const int* __restrict__ flag)
{
    const int b = blockIdx.x, t = threadIdx.x;
    if (b < HB) {
        __shared__ int hD[NBKT], hS[NBKT];
        for (int k = t; k < NBKT; k += 256) { hD[k] = 0; hS[k] = 0; }
        __syncthreads();
        ETYPE_SELECT(b);
        for (int i = lo_ + t; i < lo_ + EPS; i += 256) {
            int s = sbase_ + sp_[i];
            int d = dbase_ + dp_[i];
            atomicAdd(&hD[d >> BSH], 1);
            atomicAdd(&hS[s >> BSH], 1);
        }
        __syncthreads();
        for (int k = t; k < NBKT; k += 256) {
            tabD[b * NBKT + k] = hD[k];
            tabS[b * NBKT + k] = hS[k];
        }
    } else if (b < HB + CB) {
        if (*flag) {                   // only needed when inputs are fp32
            int base = (b - HB) * 2048 + t * 8;   // XTOT = CB*2048 exactly
            const float* xf = (base < XD_ELEMS)
                ? (const float*)x_drug + base
                : (const float*)x_gene + (base - XD_ELEMS);
            float4 a = ((const float4*)xf)[0];
            float4 c = ((const float4*)xf)[1];
            __hip_bfloat162 r[4];
            r[0] = __float22bfloat162_rn(make_float2(a.x, a.y));
            r[1] = __float22bfloat162_rn(make_float2(a.z, a.w));
            r[2] = __float22bfloat162_rn(make_float2(c.x, c.y));
            r[3] = __float22bfloat162_rn(make_float2(c.z, c.w));
            *(uint4*)(conv + base) = *(uint4*)r;
        }
    } else {
        const int isf = *flag;
        int i = (b - HB - CB) * 256 + t;          // 65536 total
        int p = i >> 15;
        int o = i & 32767;
        int j = o & 7, l = (o >> 3) & 63, nt = (o >> 9) & 7, kt = o >> 12;
        int k = kt * 32 + (l >> 4) * 8 + j;
        int n = (l & 15) * 8 + nt;     // column-permuted
        int kk = k & 127;
        const void* W;
        if (p == 0) W = (k < 128) ? W_dd : W_gd;
        else        W = (k < 128) ? W_dg : W_gg;
        float v = isf ? ((const float*)W)[kk * 128 + n]
                      : __bfloat162float(((const bf16*)W)[kk * 128 + n]);
        Bsw[i] = __float2bfloat16(v);
    }
}

// ---------------------------------------------------------------------------
// scanA: per-bucket column scan over 256 slices, COALESCED. Each block owns
// 64 columns; thread t = (quarter q, column c); two passes. Grid = 2*SAB.
// ---------------------------------------------------------------------------
__global__ __launch_bounds__(256) void scanA_kernel(
    int* __restrict__ tabD, int* __restrict__ tabS,
    int* __restrict__ btotD, int* __restrict__ btotS)
{
    __shared__ int qs[4][64];
    int t = threadIdx.x;
    int arr = blockIdx.x >= SAB;
    int blk = blockIdx.x - (arr ? SAB : 0);
    int* tab  = arr ? tabS : tabD;
    int* btot = arr ? btotS : btotD;
    int c = blk * 64 + (t & 63);
    int q = t >> 6;
    if (c >= NBKT) return;
    int sum = 0;
#pragma unroll 8
    for (int j = 0; j < 64; ++j) sum += tab[(q * 64 + j) * NBKT + c];
    qs[q][t & 63] = sum;
    __syncthreads();
    int off = 0;
    for (int qq = 0; qq < 4; ++qq) { if (qq < q) off += qs[qq][t & 63]; }
    if (q == 3) btot[c] = off + sum;
    int run = off;
#pragma unroll 8
    for (int j = 0; j < 64; ++j) {
        int idx = (q * 64 + j) * NBKT + c;
        int v = tab[idx];
        tab[idx] = run;
        run += v;
    }
}

// ---------------------------------------------------------------------------
// passB: partition edges into 256-id coarse buckets. Bucket bases computed
// IN-BLOCK (redundant 1172-scan of btot; scanB kernel eliminated). Per-block
// LDS cursors -> no global atomics. Compressed payloads:
//   ED[pos] = (d&255)<<24 | packed_src   (4 B; dst bucket is positional)
//   SK[pos] = s & 255                    (1 B; src bucket is positional)
// ---------------------------------------------------------------------------
__global__ __launch_bounds__(256) void passB_kernel(
    const int* __restrict__ src_dd, const int* __restrict__ dst_dd,
    const int* __restrict__ src_gd, const int* __restrict__ dst_gd,
    const int* __restrict__ src_dg, const int* __restrict__ dst_dg,
    const int* __restrict__ src_gg, const int* __restrict__ dst_gg,
    const int* __restrict__ tabD, const int* __restrict__ tabS,
    const int* __restrict__ btotD, const int* __restrict__ btotS,
    unsigned int* __restrict__ ED, unsigned char* __restrict__ SK)
{
    __shared__ int curD[NBKT], curS[NBKT];
    __shared__ int smD[256], smS[256];
    const int blk = blockIdx.x, t = threadIdx.x;
    // redundant exclusive scan of btotD/btotS -> bucket bases + cursor seed
    int vD[5], vS[5]; int locD = 0, locS = 0;
#pragma unroll
    for (int j = 0; j < 5; ++j) {
        int idx = t * 5 + j;
        int xD = (idx < NBKT) ? btotD[idx] : 0;
        int xS = (idx < NBKT) ? btotS[idx] : 0;
        vD[j] = locD; locD += xD;
        vS[j] = locS; locS += xS;
    }
    smD[t] = locD; smS[t] = locS;
    __syncthreads();
    for (int off = 1; off < 256; off <<= 1) {
        int uD = (t >= off) ? smD[t - off] : 0;
        int uS = (t >= off) ? smS[t - off] : 0;
        __syncthreads();
        smD[t] += uD; smS[t] += uS;
        __syncthreads();
    }
    int baseD = smD[t] - locD, baseS = smS[t] - locS;
#pragma unroll
    for (int j = 0; j < 5; ++j) {
        int idx = t * 5 + j;
        if (idx < NBKT) {
            curD[idx] = baseD + vD[j] + tabD[blk * NBKT + idx];
            curS[idx] = baseS + vS[j] + tabS[blk * NBKT + idx];
        }
    }
    __syncthreads();
    ETYPE_SELECT(blk);
    for (int i = lo_ + t; i < lo_ + EPS; i += 256) {
        int s = sbase_ + sp_[i];
        int d = dbase_ + dp_[i];
        int pD = atomicAdd(&curD[d >> BSH], 1);
        ED[pD] = ((unsigned int)(d & 255) << 24) | (unsigned int)s;
        int pS = atomicAdd(&curS[s >> BSH], 1);
        SK[pS] = (unsigned char)(s & 255);
    }
}

// ---------------------------------------------------------------------------
// Block-prefix helper: lo = sum btot[0..b), hi = lo + btot[b]   (redundant)
// ---------------------------------------------------------------------------
__device__ __forceinline__ void bucket_range(
    const int* __restrict__ btot, int b, int t, int* lohi)
{
    __shared__ int red[4];
    int p = 0;
    for (int i = t; i < b; i += 256) p += btot[i];
#pragma unroll
    for (int off = 32; off; off >>= 1) p += __shfl_down(p, off, 64);
    if ((t & 63) == 0) red[t >> 6] = p;
    __syncthreads();
    if (t == 0) {
        int lo = red[0] + red[1] + red[2] + red[3];
        lohi[0] = lo;
        lohi[1] = lo + btot[b];
    }
    __syncthreads();
}

// ---------------------------------------------------------------------------
// passCs: per-bucket exact out-degree counts from partitioned src bytes.
// ---------------------------------------------------------------------------
__global__ __launch_bounds__(256) void passCs_kernel(
    const unsigned char* __restrict__ SK, const int* __restrict__ btotS,
    int* __restrict__ deg_out)
{
    __shared__ int cnt[256];
    __shared__ int lohi[2];
    const int b = blockIdx.x, t = threadIdx.x;
    cnt[t] = 0;
    bucket_range(btotS, b, t, lohi);
    int lo = lohi[0], hi = lohi[1];
    for (int i = lo + t; i < hi; i += 256) atomicAdd(&cnt[SK[i]], 1);
    __syncthreads();
    deg_out[b * 256 + t] = cnt[t];
}

// ---------------------------------------------------------------------------
// passCd: per-bucket CSR finalize. Count 256 dst bins (LDS), in-LDS scan ->
// rp; place packed (s_local | deg_out<<17) into LDS stage in CSR order;
// flush coalesced IN-PLACE over ED (which then serves as srcnrm).
// ---------------------------------------------------------------------------
__global__ __launch_bounds__(256) void passCd_kernel(
    unsigned int* __restrict__ ED, const int* __restrict__ btotD,
    const int* __restrict__ deg_out, int* __restrict__ rp)
{
    extern __shared__ unsigned int stage[];        // CAP entries (32 KiB)
    __shared__ int cnt[256];
    __shared__ int sm[256];
    __shared__ int cur[256];
    __shared__ int lohi[2];
    const int b = blockIdx.x, t = threadIdx.x;
    cnt[t] = 0;
    bucket_range(btotD, b, t, lohi);
    int lo = lohi[0], hi = lohi[1];
    int n = hi - lo;
    for (int i = lo + t; i < hi; i += 256) atomicAdd(&cnt[ED[i] >> 24], 1);
    __syncthreads();
    int v = cnt[t];
    sm[t] = v;
    __syncthreads();
    for (int off = 1; off < 256; off <<= 1) {
        int u = (t >= off) ? sm[t - off] : 0;
        __syncthreads();
        sm[t] += u;
        __syncthreads();
    }
    int excl = sm[t] - v;
    int idx = b * 256 + t;
    if (idx < NTOT) rp[idx] = lo + excl;
    if (b == 0 && t == 0) rp[NTOT] = ETOT;
    cur[t] = excl;
    __syncthreads();
    for (int i = lo + t; i < hi; i += 256) {
        unsigned int e = ED[i];
        int s = (int)(e & 0xFFFFFF);
        int sb = (s < ND) ? 0 : (s < ND + NG) ? ND
               : (s < 2 * ND + NG) ? (ND + NG) : (2 * ND + NG);
        int pos = atomicAdd(&cur[e >> 24], 1);
        stage[pos] = (unsigned int)(s - sb) | ((unsigned int)deg_out[s] << 17);
    }
    __syncthreads();
    for (int i = t; i < n; i += 256) ED[lo + i] = stage[i];
}

// ---------------------------------------------------------------------------
// FUSED gather + GEMM + epilogue. One wave owns 16 output rows: gathers BOTH
// K-halves into a wave-private LDS A-stage [16][ALD] bf16 (stride 260 ->
// conflict-free), then runs the M=16,N=128,K=256 MFMA chain with B read
// directly from L2-resident Bsw (no B staging, no __syncthreads, no agg
// round-trip). Epilogue: bias+ReLU+L2norm, contiguous 16 B stores.
// ---------------------------------------------------------------------------
__device__ __forceinline__ void acc8(float* acc, uint4 raw, float nm)
{
    const __hip_bfloat162* p2 = (const __hip_bfloat162*)&raw;
#pragma unroll
    for (int j = 0; j < 4; ++j) {
        float2 f = __bfloat1622float2(p2[j]);
        acc[2 * j]     = fmaf(f.x, nm, acc[2 * j]);
        acc[2 * j + 1] = fmaf(f.y, nm, acc[2 * j + 1]);
    }
}

__global__ __launch_bounds__(256) void gg_kernel(
    const void* __restrict__ x_drug, const void* __restrict__ x_gene,
    const bf16* __restrict__ conv,
    const unsigned int* __restrict__ srcnrm, const int* __restrict__ rp,
    const bf16* __restrict__ Bsw, const void* __restrict__ bias,
    void* __restrict__ out_, const int* __restrict__ flag)
{
    __shared__ bf16 Ast[4][16 * ALD];    // 33280 B total
    const int isf = *flag;
    const bf16* xd = isf ? conv            : (const bf16*)x_drug;
    const bf16* xg = isf ? conv + XD_ELEMS : (const bf16*)x_gene;

    const int wv = threadIdx.x >> 6, lane = threadIdx.x & 63;
    const int phase = (blockIdx.x >= G0) ? 1 : 0;
    const int blk = phase ? blockIdx.x - G0 : blockIdx.x;
    const int rows = phase ? NG : ND;
    const int row_off = phase ? ND : 0;
    const int w0base = phase ? 2 * ND : 0;         // half0 packed-dst base
    const int w1base = phase ? 2 * ND + NG : ND;   // half1 packed-dst base
    const int r0 = blk * 64 + wv * 16;

    bf16* A = Ast[wv];
    const int g = lane >> 4;
    const int c = lane & 15;

    // ---- gather phase: 16 rows x 2 halves, wave-private ----
    for (int rr = 0; rr < 16; ++rr) {
        int r = r0 + rr;
        if (r >= rows) break;
#pragma unroll
        for (int h = 0; h < 2; ++h) {
            int w = (h ? w1base : w0base) + r;
            const bf16* x = h ? xg : xd;
            int beg = rp[w], end = rp[w + 1];
            float ndv = rsqrtf((float)max(end - beg, 1));
            float acc[8] = {};
            int i = beg + g;
            for (; i + 4 < end; i += 8) {
                unsigned int e0 = srcnrm[i];
                unsigned int e1 = srcnrm[i + 4];
                uint4 ra = *(const uint4*)(x + (size_t)(e0 & 0x1FFFF) * 128 + c * 8);
                uint4 rb = *(const uint4*)(x + (size_t)(e1 & 0x1FFFF) * 128 + c * 8);
                acc8(acc, ra, rsqrtf((float)(e0 >> 17)));
                acc8(acc, rb, rsqrtf((float)(e1 >> 17)));
            }
            if (i < end) {
                unsigned int e0 = srcnrm[i];
                uint4 ra = *(const uint4*)(x + (size_t)(e0 & 0x1FFFF) * 128 + c * 8);
                acc8(acc, ra, rsqrtf((float)(e0 >> 17)));
            }
#pragma unroll
            for (int j = 0; j < 8; ++j) {
                acc[j] += __shfl_xor(acc[j], 16, 64);
                acc[j] += __shfl_xor(acc[j], 32, 64);
            }
            if (g == 0) {
                __hip_bfloat162 o[4];
#pragma unroll
                for (int j = 0; j < 4; ++j)
                    o[j] = __float22bfloat162_rn(
                        make_float2(acc[2 * j] * ndv, acc[2 * j + 1] * ndv));
                *(uint4*)(A + rr * ALD + h * 128 + c * 8) = *(uint4*)o;
            }
        }
    }

    // ---- MFMA phase: M=16, N=128, K=256; B direct from L2 ----
    const bf16* Bp = Bsw + phase * 32768;
    f32x4 acc2[8];
#pragma unroll
    for (int nt = 0; nt < 8; ++nt) acc2[nt] = (f32x4){0.f, 0.f, 0.f, 0.f};

    const int arow = lane & 15;
    const int koff = (lane >> 4) * 8;
#pragma unroll
    for (int kt = 0; kt < 8; ++kt) {
        bf16x8 a = *(const bf16x8*)(A + arow * ALD + kt * 32 + koff);
#pragma unroll
        for (int nt = 0; nt < 8; ++nt) {
            bf16x8 b = *(const bf16x8*)(Bp + ((kt * 8 + nt) * 64 + lane) * 8);
            acc2[nt] = __builtin_amdgcn_mfma_f32_16x16x32_bf16(a, b, acc2[nt], 0, 0, 0);
        }
    }

    // ---- epilogue: bias + ReLU + L2 norm + store ----
    const int ncol = lane & 15;
    float bv[8];
#pragma unroll
    for (int nt = 0; nt < 8; ++nt)
        bv[nt] = isf ? ((const float*)bias)[ncol * 8 + nt]
                     : __bfloat162float(((const bf16*)bias)[ncol * 8 + nt]);

#pragma unroll
    for (int reg = 0; reg < 4; ++reg) {
        int row = r0 + (lane >> 4) * 4 + reg;
        float h[8]; float ss = 0.f;
#pragma unroll
        for (int nt = 0; nt < 8; ++nt) {
            float v = acc2[nt][reg] + bv[nt];
            v = fmaxf(v, 0.f);
            h[nt] = v;
            ss = fmaf(v, v, ss);
        }
        ss += __shfl_xor(ss, 1, 64);
        ss += __shfl_xor(ss, 2, 64);
        ss += __shfl_xor(ss, 4, 64);
        ss += __shfl_xor(ss, 8, 64);
        float sc = 1.0f / fmaxf(sqrtf(ss), 1e-12f);
        if (row < rows) {
            size_t ob = (size_t)(row + row_off) * NF + ncol * 8;
            if (isf) {
                float* op = (float*)out_ + ob;
                *(float4*)op = make_float4(h[0]*sc, h[1]*sc, h[2]*sc, h[3]*sc);
                *(float4*)(op + 4) = make_float4(h[4]*sc, h[5]*sc, h[6]*sc, h[7]*sc);
            } else {
                bf16* op = (bf16*)out_ + ob;
                __hip_bfloat162 o[4];
#pragma unroll
                for (int j = 0; j < 4; ++j)
                    o[j] = __float22bfloat162_rn(
                        make_float2(h[2*j] * sc, h[2*j+1] * sc));
                *(uint4*)op = *(uint4*)o;
            }
        }
    }
}

// ---------------------------------------------------------------------------
extern "C" void kernel_launch(void* const* d_in, const int* in_sizes, int n_in,
                              void* d_out, int out_size, void* d_ws, size_t ws_size,
                              hipStream_t stream)
{
    const void* x_drug = d_in[0];
    const void* x_gene = d_in[1];
    const void* W_dd   = d_in[2];
    const void* W_dg   = d_in[3];
    const void* W_gd   = d_in[4];
    const void* W_gg   = d_in[5];
    const void* h_bias = d_in[6];
    const int* src_dd = (const int*)d_in[7];
    const int* dst_dd = (const int*)d_in[8];
    const int* src_dg = (const int*)d_in[9];
    const int* dst_dg = (const int*)d_in[10];
    const int* src_gd = (const int*)d_in[11];
    const int* dst_gd = (const int*)d_in[12];
    const int* src_gg = (const int*)d_in[13];
    const int* dst_gg = (const int*)d_in[14];

    // ---- workspace layout (agg buffers eliminated by fusion) ----
    bf16* Bsw  = (bf16*)d_ws;                 // [2][32768]
    bf16* conv = Bsw + 65536;                 // [XTOT] bf16 x copy
    int*  ib   = (int*)(conv + XTOT);
    int* tabD    = ib;                        // [256][1172] = 300032
    int* tabS    = ib + 300032;               // 300032 -> 600064
    int* btotD   = ib + 600064;               // 1172   -> 601236
    int* btotS   = ib + 601236;               // 1172   -> 602408
    int* deg_out = ib + 602408;               // 300032 -> 902440
    int* rp_all  = ib + 902440;               // 300001 -> 1202441
    int* flag    = ib + 1202441;              // 1      -> 1202442
    unsigned int*  ED = (unsigned int*)(ib + 1202442);  // 2400000 -> 3602442
    unsigned char* SK = (unsigned char*)(ib + 3602442); // 2400000 B -> 4202442
                                              // end: ib + 4202442 ints

    size_t needed = 131072 + (size_t)XTOT * 2 + 4202442ull * 4;
    if (ws_size < needed) {
        hipMemsetAsync(d_out, 0, (size_t)out_size * 2, stream);
        return;
    }

    const int TB = 256;

    detect_kernel<<<1, 64, 0, stream>>>(x_drug, flag);

    pre_kernel<<<HB + CB + PB, TB, 0, stream>>>(
        src_dd, dst_dd, src_gd, dst_gd, src_dg, dst_dg, src_gg, dst_gg,
        tabD, tabS, x_drug, x_gene, conv,
        W_dd, W_gd, W_dg, W_gg, Bsw, flag);

    scanA_kernel<<<2 * SAB, TB, 0, stream>>>(tabD, tabS, btotD, btotS);

    passB_kernel<<<HB, TB, 0, stream>>>(
        src_dd, dst_dd, src_gd, dst_gd, src_dg, dst_dg, src_gg, dst_gg,
        tabD, tabS, btotD, btotS, ED, SK);

    passCs_kernel<<<NBKT, TB, 0, stream>>>(SK, btotS, deg_out);

    passCd_kernel<<<NBKT, TB, CAP * sizeof(unsigned int), stream>>>(
        ED, btotD, deg_out, rp_all);

    gg_kernel<<<G0 + G1, TB, 0, stream>>>(
        x_drug, x_gene, conv, ED, rp_all, Bsw, h_bias, d_out, flag);
}

// Round 5
// 379.864 us; speedup vs baseline: 1.1869x; 1.1869x over previous
//
#include <hip/hip_runtime.h>
#include <hip/hip_bf16.h>

#define ND 100000
#define NG 50000
#define NF 128
#define NE 600000
#define NTOT 300000          // packed dst rows  [dd(100k) | gd(100k) | dg(50k) | gg(50k)]
#define ETOT 2400000         // 4*NE
#define XD_ELEMS 12800000    // ND*NF
#define XTOT 19200000        // (ND+NG)*NF
#define CB 9375              // XTOT/2048 blocks (convert role)
#define PB 256               // weight-prep role blocks
#define HB 256               // histogram role blocks (= edge slices)
#define EPS 9375             // edges per slice (64 slices per etype)
#define NBKT 1172            // ceil(300032/256): dst/src buckets of 256 ids
#define BSH 8                // bucket = id >> 8
#define CAP 8192             // passC LDS stage capacity (max bucket ~3350)
#define SAB 19               // scanA blocks per table = ceil(NBKT/64)
#define G0 3125              // ND/32 fused-kernel drug blocks (32 rows/block)
#define G1 1563              // ceil(NG/32) fused-kernel gene blocks
#define ALD 260              // A-stage LDS row stride (bf16): 520 B -> conflict-free

typedef __hip_bfloat16 bf16;
typedef __attribute__((ext_vector_type(8))) short bf16x8;
typedef __attribute__((ext_vector_type(4))) float f32x4;

// ---------------------------------------------------------------------------
// Inline dtype detector (replaces detect_kernel; saves a dispatch).
// fp32 data read as u16 halfwords: mantissa-low halves look like bf16 with
// huge exponents; genuine bf16 N(0,1) never has exp>=137 (|x|>=2^10).
// Wave-uniform (__any over 64 lanes x 16 halfwords = 1024 probed), no barrier.
// ---------------------------------------------------------------------------
__device__ __forceinline__ int detect_fp32(const void* __restrict__ x)
{
    const unsigned short* u = (const unsigned short*)x;
    int l = threadIdx.x & 63;
    int found = 0;
#pragma unroll
    for (int i = 0; i < 16; ++i) {
        unsigned short v = u[l * 16 + i];
        if (((v >> 7) & 0xFF) >= 137) found = 1;
    }
    return __any(found) ? 1 : 0;
}

// ---------------------------------------------------------------------------
// Etype select helper: slice blk in [0,256), 64 slices per etype.
// ---------------------------------------------------------------------------
#define ETYPE_SELECT(blk)                                                     \
    const int e_ = (blk) >> 6;                                                \
    const int lo_ = ((blk) & 63) * EPS;                                       \
    const int *sp_, *dp_; int sbase_, dbase_;                                 \
    if (e_ == 0)      { sp_ = src_dd; dp_ = dst_dd; sbase_ = 0;         dbase_ = 0; }          \
    else if (e_ == 1) { sp_ = src_gd; dp_ = dst_gd; sbase_ = ND;        dbase_ = ND; }         \
    else if (e_ == 2) { sp_ = src_dg; dp_ = dst_dg; sbase_ = ND + NG;   dbase_ = 2 * ND; }     \
    else              { sp_ = src_gg; dp_ = dst_gg; sbase_ = 2*ND+NG;   dbase_ = 2*ND + NG; }

// ---------------------------------------------------------------------------
// Fused pre-pass (NO global atomics), three block-ranges:
//   [0,HB)        PassA: per-slice LDS histograms over 1172 coarse buckets
//   [HB,HB+CB)    x fp32 -> bf16 conversion (skipped if bf16 input)
//   [+PB)         MFMA-swizzled B prep: Bsw[2][256k][128n], n column-permuted
// ---------------------------------------------------------------------------
__global__ __launch_bounds__(256) void pre_kernel(
    const int* __restrict__ src_dd, const int* __restrict__ dst_dd,
    const int* __restrict__ src_gd, const int* __restrict__ dst_gd,
    const int* __restrict__ src_dg, const int* __restrict__ dst_dg,
    const int* __restrict__ src_gg, const int* __restrict__ dst_gg,
    int* __restrict__ tabD, int* __restrict__ tabS,   // [HB][NBKT]
    const void* __restrict__ x_drug, const void* __restrict__ x_gene,
    bf16* __restrict__ conv,
    const void* __restrict__ W_dd, const void* __restrict__ W_gd,
    const void* __restrict__ W_dg, const void* __restrict__ W_gg,
    bf16* __restrict__ Bsw)
{
    const int b = blockIdx.x, t = threadIdx.x;
    if (b < HB) {
        __shared__ int hD[NBKT], hS[NBKT];
        for (int k = t; k < NBKT; k += 256) { hD[k] = 0; hS[k] = 0; }
        __syncthreads();
        ETYPE_SELECT(b);
        for (int i = lo_ + t; i < lo_ + EPS; i += 256) {
            int s = sbase_ + sp_[i];
            int d = dbase_ + dp_[i];
            atomicAdd(&hD[d >> BSH], 1);
            atomicAdd(&hS[s >> BSH], 1);
        }
        __syncthreads();
        for (int k = t; k < NBKT; k += 256) {
            tabD[b * NBKT + k] = hD[k];
            tabS[b * NBKT + k] = hS[k];
        }
    } else if (b < HB + CB) {
        if (detect_fp32(x_drug)) {     // only needed when inputs are fp32
            int base = (b - HB) * 2048 + t * 8;   // XTOT = CB*2048 exactly
            const float* xf = (base < XD_ELEMS)
                ? (const float*)x_drug + base
                : (const float*)x_gene + (base - XD_ELEMS);
            float4 a = ((const float4*)xf)[0];
            float4 c = ((const float4*)xf)[1];
            __hip_bfloat162 r[4];
            r[0] = __float22bfloat162_rn(make_float2(a.x, a.y));
            r[1] = __float22bfloat162_rn(make_float2(a.z, a.w));
            r[2] = __float22bfloat162_rn(make_float2(c.x, c.y));
            r[3] = __float22bfloat162_rn(make_float2(c.z, c.w));
            *(uint4*)(conv + base) = *(uint4*)r;
        }
    } else {
        const int isf = detect_fp32(x_drug);
        int i = (b - HB - CB) * 256 + t;          // 65536 total
        int p = i >> 15;
        int o = i & 32767;
        int j = o & 7, l = (o >> 3) & 63, nt = (o >> 9) & 7, kt = o >> 12;
        int k = kt * 32 + (l >> 4) * 8 + j;
        int n = (l & 15) * 8 + nt;     // column-permuted
        int kk = k & 127;
        const void* W;
        if (p == 0) W = (k < 128) ? W_dd : W_gd;
        else        W = (k < 128) ? W_dg : W_gg;
        float v = isf ? ((const float*)W)[kk * 128 + n]
                      : __bfloat162float(((const bf16*)W)[kk * 128 + n]);
        Bsw[i] = __float2bfloat16(v);
    }
}

// ---------------------------------------------------------------------------
// scanA: per-bucket column scan over 256 slices, COALESCED. Each block owns
// 64 columns; thread t = (quarter q, column c); two passes. Grid = 2*SAB.
// ---------------------------------------------------------------------------
__global__ __launch_bounds__(256) void scanA_kernel(
    int* __restrict__ tabD, int* __restrict__ tabS,
    int* __restrict__ btotD, int* __restrict__ btotS)
{
    __shared__ int qs[4][64];
    int t = threadIdx.x;
    int arr = blockIdx.x >= SAB;
    int blk = blockIdx.x - (arr ? SAB : 0);
    int* tab  = arr ? tabS : tabD;
    int* btot = arr ? btotS : btotD;
    int c = blk * 64 + (t & 63);
    int q = t >> 6;
    if (c >= NBKT) return;
    int sum = 0;
#pragma unroll 8
    for (int j = 0; j < 64; ++j) sum += tab[(q * 64 + j) * NBKT + c];
    qs[q][t & 63] = sum;
    __syncthreads();
    int off = 0;
    for (int qq = 0; qq < 4; ++qq) { if (qq < q) off += qs[qq][t & 63]; }
    if (q == 3) btot[c] = off + sum;
    int run = off;
#pragma unroll 8
    for (int j = 0; j < 64; ++j) {
        int idx = (q * 64 + j) * NBKT + c;
        int v = tab[idx];
        tab[idx] = run;
        run += v;
    }
}

// ---------------------------------------------------------------------------
// passB: partition edges into 256-id coarse buckets. Bucket bases computed
// in-block (redundant scan of btot). Per-block LDS cursors, no global
// atomics. Payloads: ED[pos] = (d&255)<<24 | packed_src ; SK[pos] = s&255.
// ---------------------------------------------------------------------------
__global__ __launch_bounds__(256) void passB_kernel(
    const int* __restrict__ src_dd, const int* __restrict__ dst_dd,
    const int* __restrict__ src_gd, const int* __restrict__ dst_gd,
    const int* __restrict__ src_dg, const int* __restrict__ dst_dg,
    const int* __restrict__ src_gg, const int* __restrict__ dst_gg,
    const int* __restrict__ tabD, const int* __restrict__ tabS,
    const int* __restrict__ btotD, const int* __restrict__ btotS,
    unsigned int* __restrict__ ED, unsigned char* __restrict__ SK)
{
    __shared__ int curD[NBKT], curS[NBKT];
    __shared__ int smD[256], smS[256];
    const int blk = blockIdx.x, t = threadIdx.x;
    int vD[5], vS[5]; int locD = 0, locS = 0;
#pragma unroll
    for (int j = 0; j < 5; ++j) {
        int idx = t * 5 + j;
        int xD = (idx < NBKT) ? btotD[idx] : 0;
        int xS = (idx < NBKT) ? btotS[idx] : 0;
        vD[j] = locD; locD += xD;
        vS[j] = locS; locS += xS;
    }
    smD[t] = locD; smS[t] = locS;
    __syncthreads();
    for (int off = 1; off < 256; off <<= 1) {
        int uD = (t >= off) ? smD[t - off] : 0;
        int uS = (t >= off) ? smS[t - off] : 0;
        __syncthreads();
        smD[t] += uD; smS[t] += uS;
        __syncthreads();
    }
    int baseD = smD[t] - locD, baseS = smS[t] - locS;
#pragma unroll
    for (int j = 0; j < 5; ++j) {
        int idx = t * 5 + j;
        if (idx < NBKT) {
            curD[idx] = baseD + vD[j] + tabD[blk * NBKT + idx];
            curS[idx] = baseS + vS[j] + tabS[blk * NBKT + idx];
        }
    }
    __syncthreads();
    ETYPE_SELECT(blk);
    for (int i = lo_ + t; i < lo_ + EPS; i += 256) {
        int s = sbase_ + sp_[i];
        int d = dbase_ + dp_[i];
        int pD = atomicAdd(&curD[d >> BSH], 1);
        ED[pD] = ((unsigned int)(d & 255) << 24) | (unsigned int)s;
        int pS = atomicAdd(&curS[s >> BSH], 1);
        SK[pS] = (unsigned char)(s & 255);
    }
}

// ---------------------------------------------------------------------------
// Block-prefix helper: lo = sum btot[0..b), hi = lo + btot[b]   (redundant)
// ---------------------------------------------------------------------------
__device__ __forceinline__ void bucket_range(
    const int* __restrict__ btot, int b, int t, int* lohi)
{
    __shared__ int red[4];
    int p = 0;
    for (int i = t; i < b; i += 256) p += btot[i];
#pragma unroll
    for (int off = 32; off; off >>= 1) p += __shfl_down(p, off, 64);
    if ((t & 63) == 0) red[t >> 6] = p;
    __syncthreads();
    if (t == 0) {
        int lo = red[0] + red[1] + red[2] + red[3];
        lohi[0] = lo;
        lohi[1] = lo + btot[b];
    }
    __syncthreads();
}

// ---------------------------------------------------------------------------
// passC: MERGED (saves a dispatch). Two block-ranges, independent:
//   [0,NBKT)        Cs: per-bucket out-degree counts from partitioned SK
//   [NBKT,2*NBKT)   Cd: CSR finalize — fine dst counts, in-LDS scan -> rp,
//                   reorder bucket edges into exact CSR order IN-PLACE over
//                   ED, storing raw packed src (deg looked up by the gather).
// ---------------------------------------------------------------------------
__global__ __launch_bounds__(256) void passC_kernel(
    unsigned int* __restrict__ ED, const unsigned char* __restrict__ SK,
    const int* __restrict__ btotD, const int* __restrict__ btotS,
    int* __restrict__ deg_out, int* __restrict__ rp)
{
    extern __shared__ unsigned int stage[];        // CAP entries (32 KiB)
    __shared__ int cnt[256];
    __shared__ int sm[256];
    __shared__ int cur[256];
    __shared__ int lohi[2];
    const int t = threadIdx.x;
    if (blockIdx.x < NBKT) {
        const int b = blockIdx.x;
        cnt[t] = 0;
        bucket_range(btotS, b, t, lohi);
        int lo = lohi[0], hi = lohi[1];
        for (int i = lo + t; i < hi; i += 256) atomicAdd(&cnt[SK[i]], 1);
        __syncthreads();
        deg_out[b * 256 + t] = cnt[t];
        return;
    }
    const int b = blockIdx.x - NBKT;
    cnt[t] = 0;
    bucket_range(btotD, b, t, lohi);
    int lo = lohi[0], hi = lohi[1];
    int n = hi - lo;
    for (int i = lo + t; i < hi; i += 256) atomicAdd(&cnt[ED[i] >> 24], 1);
    __syncthreads();
    int v = cnt[t];
    sm[t] = v;
    __syncthreads();
    for (int off = 1; off < 256; off <<= 1) {
        int u = (t >= off) ? sm[t - off] : 0;
        __syncthreads();
        sm[t] += u;
        __syncthreads();
    }
    int excl = sm[t] - v;
    int idx = b * 256 + t;
    if (idx < NTOT) rp[idx] = lo + excl;
    if (b == 0 && t == 0) rp[NTOT] = ETOT;
    cur[t] = excl;
    __syncthreads();
    for (int i = lo + t; i < hi; i += 256) {
        unsigned int e = ED[i];
        int pos = atomicAdd(&cur[e >> 24], 1);
        stage[pos] = e & 0xFFFFFF;     // raw packed src
    }
    __syncthreads();
    for (int i = t; i < n; i += 256) ED[lo + i] = stage[i];
}

// ---------------------------------------------------------------------------
// FUSED gather + GEMM + epilogue, occupancy-fixed: a WAVE PAIR shares one
// 16-row A-tile (each wave gathers 8 rows x 2 K-halves into LDS), then both
// waves run the M=16,K=256 MFMA with an N=64 split each (B direct from
// L2-resident Bsw). LDS/block = 2 tiles x 16 x 260 x 2B = 16.6 KB ->
// 8 blocks/CU. Row L2-norm: cross-wave partial exchange via 256 B LDS.
// ---------------------------------------------------------------------------
__device__ __forceinline__ void acc8(float* acc, uint4 raw, float nm)
{
    const __hip_bfloat162* p2 = (const __hip_bfloat162*)&raw;
#pragma unroll
    for (int j = 0; j < 4; ++j) {
        float2 f = __bfloat1622float2(p2[j]);
        acc[2 * j]     = fmaf(f.x, nm, acc[2 * j]);
        acc[2 * j + 1] = fmaf(f.y, nm, acc[2 * j + 1]);
    }
}

__global__ __launch_bounds__(256, 8) void gg_kernel(
    const void* __restrict__ x_drug, const void* __restrict__ x_gene,
    const bf16* __restrict__ conv,
    const unsigned int* __restrict__ srcp, const int* __restrict__ rp,
    const int* __restrict__ deg_out,
    const bf16* __restrict__ Bsw, const void* __restrict__ bias,
    void* __restrict__ out_)
{
    __shared__ bf16 Ast[2][16 * ALD];     // 16640 B
    __shared__ float ssx[2][2][4][4];     // [pair][wvh][grp][reg]
    const int isf = detect_fp32(x_drug);
    const bf16* xd = isf ? conv            : (const bf16*)x_drug;
    const bf16* xg = isf ? conv + XD_ELEMS : (const bf16*)x_gene;

    const int wv = threadIdx.x >> 6, lane = threadIdx.x & 63;
    const int pair = wv >> 1, wvh = wv & 1;
    const int phase = (blockIdx.x >= G0) ? 1 : 0;
    const int blk = phase ? blockIdx.x - G0 : blockIdx.x;
    const int rows = phase ? NG : ND;
    const int row_off = phase ? ND : 0;
    const int w0base = phase ? 2 * ND : 0;         // half0 packed-dst base
    const int w1base = phase ? 2 * ND + NG : ND;   // half1 packed-dst base
    const int s0base = phase ? ND + NG : 0;        // half0 packed-src base
    const int s1base = phase ? 2 * ND + NG : ND;   // half1 packed-src base
    const int r0 = blk * 32 + pair * 16;

    bf16* A = Ast[pair];
    const int g = lane >> 4;
    const int c = lane & 15;

    // x pointers pre-offset by packed-src base: index directly with s_packed
    const bf16* xh[2] = { (phase ? xd : xd) - (size_t)s0base * 128,
                          xg - (size_t)s1base * 128 };
    const int wb[2] = { w0base, w1base };

    // ---- gather phase: 8 rows x 2 halves per wave into the shared tile ----
    for (int rr = 0; rr < 8; ++rr) {
        int r = r0 + wvh * 8 + rr;
        int trow = wvh * 8 + rr;
#pragma unroll
        for (int h = 0; h < 2; ++h) {
            if (r >= rows) {
                if (g == 0) *(uint4*)(A + trow * ALD + h * 128 + c * 8) =
                    make_uint4(0, 0, 0, 0);
                continue;
            }
            int w = wb[h] + r;
            const bf16* x = xh[h];
            int beg = rp[w], end = rp[w + 1];
            float ndv = rsqrtf((float)max(end - beg, 1));
            float acc[8] = {};
            int i = beg + g;
            for (; i + 4 < end; i += 8) {
                unsigned int s0 = srcp[i];
                unsigned int s1 = srcp[i + 4];
                uint4 ra = *(const uint4*)(x + (size_t)s0 * 128 + c * 8);
                uint4 rb = *(const uint4*)(x + (size_t)s1 * 128 + c * 8);
                float d0 = (float)max(deg_out[s0], 1);
                float d1 = (float)max(deg_out[s1], 1);
                acc8(acc, ra, rsqrtf(d0));
                acc8(acc, rb, rsqrtf(d1));
            }
            if (i < end) {
                unsigned int s0 = srcp[i];
                uint4 ra = *(const uint4*)(x + (size_t)s0 * 128 + c * 8);
                float d0 = (float)max(deg_out[s0], 1);
                acc8(acc, ra, rsqrtf(d0));
            }
#pragma unroll
            for (int j = 0; j < 8; ++j) {
                acc[j] += __shfl_xor(acc[j], 16, 64);
                acc[j] += __shfl_xor(acc[j], 32, 64);
            }
            if (g == 0) {
                __hip_bfloat162 o[4];
#pragma unroll
                for (int j = 0; j < 4; ++j)
                    o[j] = __float22bfloat162_rn(
                        make_float2(acc[2 * j] * ndv, acc[2 * j + 1] * ndv));
                *(uint4*)(A + trow * ALD + h * 128 + c * 8) = *(uint4*)o;
            }
        }
    }
    __syncthreads();

    // ---- MFMA phase: M=16, N=64 per wave (wvh picks nt-half), K=256 ----
    const bf16* Bp = Bsw + phase * 32768;
    f32x4 acc2[4];
#pragma unroll
    for (int nt = 0; nt < 4; ++nt) acc2[nt] = (f32x4){0.f, 0.f, 0.f, 0.f};

    const int arow = lane & 15;
    const int koff = (lane >> 4) * 8;
#pragma unroll
    for (int kt = 0; kt < 8; ++kt) {
        bf16x8 a = *(const bf16x8*)(A + arow * ALD + kt * 32 + koff);
#pragma unroll
        for (int nt = 0; nt < 4; ++nt) {
            int ntg = wvh * 4 + nt;
            bf16x8 b = *(const bf16x8*)(Bp + ((kt * 8 + ntg) * 64 + lane) * 8);
            acc2[nt] = __builtin_amdgcn_mfma_f32_16x16x32_bf16(a, b, acc2[nt], 0, 0, 0);
        }
    }

    // ---- epilogue: bias + ReLU, cross-wave L2-norm, contiguous stores ----
    const int ncol = lane & 15;
    const int grp = lane >> 4;
    float bv[4];
#pragma unroll
    for (int nt = 0; nt < 4; ++nt)
        bv[nt] = isf ? ((const float*)bias)[ncol * 8 + wvh * 4 + nt]
                     : __bfloat162float(((const bf16*)bias)[ncol * 8 + wvh * 4 + nt]);

    float h[4][4]; float ssp[4];
#pragma unroll
    for (int reg = 0; reg < 4; ++reg) {
        float ss = 0.f;
#pragma unroll
        for (int nt = 0; nt < 4; ++nt) {
            float v = acc2[nt][reg] + bv[nt];
            v = fmaxf(v, 0.f);
            h[reg][nt] = v;
            ss = fmaf(v, v, ss);
        }
        ss += __shfl_xor(ss, 1, 64);
        ss += __shfl_xor(ss, 2, 64);
        ss += __shfl_xor(ss, 4, 64);
        ss += __shfl_xor(ss, 8, 64);
        ssp[reg] = ss;
        if (ncol == 0) ssx[pair][wvh][grp][reg] = ss;
    }
    __syncthreads();
#pragma unroll
    for (int reg = 0; reg < 4; ++reg) {
        int row = r0 + grp * 4 + reg;
        float sst = ssp[reg] + ssx[pair][wvh ^ 1][grp][reg];
        float sc = 1.0f / fmaxf(sqrtf(sst), 1e-12f);
        if (row < rows) {
            size_t ob = (size_t)(row + row_off) * NF + ncol * 8 + wvh * 4;
            if (isf) {
                float* op = (float*)out_ + ob;
                *(float4*)op = make_float4(h[reg][0] * sc, h[reg][1] * sc,
                                           h[reg][2] * sc, h[reg][3] * sc);
            } else {
                bf16* op = (bf16*)out_ + ob;
                __hip_bfloat162 o[2];
                o[0] = __float22bfloat162_rn(make_float2(h[reg][0] * sc, h[reg][1] * sc));
                o[1] = __float22bfloat162_rn(make_float2(h[reg][2] * sc, h[reg][3] * sc));
                *(uint2*)op = *(uint2*)o;
            }
        }
    }
}

// ---------------------------------------------------------------------------
extern "C" void kernel_launch(void* const* d_in, const int* in_sizes, int n_in,
                              void* d_out, int out_size, void* d_ws, size_t ws_size,
                              hipStream_t stream)
{
    const void* x_drug = d_in[0];
    const void* x_gene = d_in[1];
    const void* W_dd   = d_in[2];
    const void* W_dg   = d_in[3];
    const void* W_gd   = d_in[4];
    const void* W_gg   = d_in[5];
    const void* h_bias = d_in[6];
    const int* src_dd = (const int*)d_in[7];
    const int* dst_dd = (const int*)d_in[8];
    const int* src_dg = (const int*)d_in[9];
    const int* dst_dg = (const int*)d_in[10];
    const int* src_gd = (const int*)d_in[11];
    const int* dst_gd = (const int*)d_in[12];
    const int* src_gg = (const int*)d_in[13];
    const int* dst_gg = (const int*)d_in[14];

    // ---- workspace layout ----
    bf16* Bsw  = (bf16*)d_ws;                 // [2][32768]
    bf16* conv = Bsw + 65536;                 // [XTOT] bf16 x copy
    int*  ib   = (int*)(conv + XTOT);
    int* tabD    = ib;                        // [256][1172] = 300032
    int* tabS    = ib + 300032;               // 300032 -> 600064
    int* btotD   = ib + 600064;               // 1172   -> 601236
    int* btotS   = ib + 601236;               // 1172   -> 602408
    int* deg_out = ib + 602408;               // 300032 -> 902440
    int* rp_all  = ib + 902440;               // 300001 -> 1202441
    unsigned int*  ED = (unsigned int*)(ib + 1202441);  // 2400000 -> 3602441
    unsigned char* SK = (unsigned char*)(ib + 3602441); // 2400000 B -> 4202441
                                              // end: ib + 4202441 ints

    size_t needed = 131072 + (size_t)XTOT * 2 + 4202441ull * 4;
    if (ws_size < needed) {
        hipMemsetAsync(d_out, 0, (size_t)out_size * 2, stream);
        return;
    }

    const int TB = 256;

    pre_kernel<<<HB + CB + PB, TB, 0, stream>>>(
        src_dd, dst_dd, src_gd, dst_gd, src_dg, dst_dg, src_gg, dst_gg,
        tabD, tabS, x_drug, x_gene, conv,
        W_dd, W_gd, W_dg, W_gg, Bsw);

    scanA_kernel<<<2 * SAB, TB, 0, stream>>>(tabD, tabS, btotD, btotS);

    passB_kernel<<<HB, TB, 0, stream>>>(
        src_dd, dst_dd, src_gd, dst_gd, src_dg, dst_dg, src_gg, dst_gg,
        tabD, tabS, btotD, btotS, ED, SK);

    passC_kernel<<<2 * NBKT, TB, CAP * sizeof(unsigned int), stream>>>(
        ED, SK, btotD, btotS, deg_out, rp_all);

    gg_kernel<<<G0 + G1, TB, 0, stream>>>(
        x_drug, x_gene, conv, ED, rp_all, deg_out, Bsw, h_bias, d_out);
}

// Round 7
// 366.687 us; speedup vs baseline: 1.2296x; 1.0359x over previous
//
#include <hip/hip_runtime.h>
#include <hip/hip_bf16.h>

#define ND 100000
#define NG 50000
#define NF 128
#define NE 600000
#define NTOT 300000          // packed dst rows  [dd(100k) | gd(100k) | dg(50k) | gg(50k)]
#define ETOT 2400000         // 4*NE
#define XD_ELEMS 12800000    // ND*NF
#define XTOT 19200000        // (ND+NG)*NF
#define CB 9375              // XTOT/2048 blocks (convert role)
#define PB 256               // weight-prep role blocks
#define HB 256               // histogram role blocks (= edge slices)
#define EPS 9375             // edges per slice (64 slices per etype)
#define NBKT 1172            // ceil(300032/256): dst/src buckets of 256 ids
#define BSH 8                // bucket = id >> 8
#define CAP 8192             // passC LDS stage capacity (max bucket ~3350)
#define SAB 19               // scanA blocks per table = ceil(NBKT/64)
#define G0 3125              // ND/32 fused-kernel drug blocks (32 rows/block)
#define G1 1563              // ceil(NG/32) fused-kernel gene blocks
#define ALD 260              // A-stage LDS row stride (bf16): 520 B -> conflict-free

typedef __hip_bfloat16 bf16;
typedef __attribute__((ext_vector_type(8))) short bf16x8;
typedef __attribute__((ext_vector_type(4))) float f32x4;

// ---------------------------------------------------------------------------
// Inline dtype detector. fp32 data read as u16 halfwords: mantissa-low halves
// look like bf16 with huge exponents; genuine bf16 N(0,1) never has exp>=137.
// Wave-uniform (__any over 64 lanes x 16 halfwords), no barrier.
// ---------------------------------------------------------------------------
__device__ __forceinline__ int detect_fp32(const void* __restrict__ x)
{
    const unsigned short* u = (const unsigned short*)x;
    int l = threadIdx.x & 63;
    int found = 0;
#pragma unroll
    for (int i = 0; i < 16; ++i) {
        unsigned short v = u[l * 16 + i];
        if (((v >> 7) & 0xFF) >= 137) found = 1;
    }
    return __any(found) ? 1 : 0;
}

// ---------------------------------------------------------------------------
// Etype select helper: slice blk in [0,256), 64 slices per etype.
// ---------------------------------------------------------------------------
#define ETYPE_SELECT(blk)                                                     \
    const int e_ = (blk) >> 6;                                                \
    const int lo_ = ((blk) & 63) * EPS;                                       \
    const int *sp_, *dp_; int sbase_, dbase_;                                 \
    if (e_ == 0)      { sp_ = src_dd; dp_ = dst_dd; sbase_ = 0;         dbase_ = 0; }          \
    else if (e_ == 1) { sp_ = src_gd; dp_ = dst_gd; sbase_ = ND;        dbase_ = ND; }         \
    else if (e_ == 2) { sp_ = src_dg; dp_ = dst_dg; sbase_ = ND + NG;   dbase_ = 2 * ND; }     \
    else              { sp_ = src_gg; dp_ = dst_gg; sbase_ = 2*ND+NG;   dbase_ = 2*ND + NG; }

// ---------------------------------------------------------------------------
// Fused pre-pass (NO global atomics), three block-ranges:
//   [0,HB)        PassA: per-slice LDS histograms over 1172 coarse buckets
//   [HB,HB+CB)    x fp32 -> bf16 conversion (skipped if bf16 input)
//   [+PB)         MFMA-swizzled B prep: Bsw[2][256k][128n]. Column mapping:
//                 slot (nt, q=l&15) holds col (nt>>2)*64 + q*4 + (nt&3) so
//                 each wave-half owns a CONTIGUOUS 64-col span (coalesced
//                 epilogue stores: lane q writes 4 adjacent cols).
// ---------------------------------------------------------------------------
__global__ __launch_bounds__(256) void pre_kernel(
    const int* __restrict__ src_dd, const int* __restrict__ dst_dd,
    const int* __restrict__ src_gd, const int* __restrict__ dst_gd,
    const int* __restrict__ src_dg, const int* __restrict__ dst_dg,
    const int* __restrict__ src_gg, const int* __restrict__ dst_gg,
    int* __restrict__ tabD, int* __restrict__ tabS,   // [HB][NBKT]
    const void* __restrict__ x_drug, const void* __restrict__ x_gene,
    bf16* __restrict__ conv,
    const void* __restrict__ W_dd, const void* __restrict__ W_gd,
    const void* __restrict__ W_dg, const void* __restrict__ W_gg,
    bf16* __restrict__ Bsw)
{
    const int b = blockIdx.x, t = threadIdx.x;
    if (b < HB) {
        __shared__ int hD[NBKT], hS[NBKT];
        for (int k = t; k < NBKT; k += 256) { hD[k] = 0; hS[k] = 0; }
        __syncthreads();
        ETYPE_SELECT(b);
        for (int i = lo_ + t; i < lo_ + EPS; i += 256) {
            int s = sbase_ + sp_[i];
            int d = dbase_ + dp_[i];
            atomicAdd(&hD[d >> BSH], 1);
            atomicAdd(&hS[s >> BSH], 1);
        }
        __syncthreads();
        for (int k = t; k < NBKT; k += 256) {
            tabD[b * NBKT + k] = hD[k];
            tabS[b * NBKT + k] = hS[k];
        }
    } else if (b < HB + CB) {
        if (detect_fp32(x_drug)) {     // only needed when inputs are fp32
            int base = (b - HB) * 2048 + t * 8;   // XTOT = CB*2048 exactly
            const float* xf = (base < XD_ELEMS)
                ? (const float*)x_drug + base
                : (const float*)x_gene + (base - XD_ELEMS);
            float4 a = ((const float4*)xf)[0];
            float4 c = ((const float4*)xf)[1];
            __hip_bfloat162 r[4];
            r[0] = __float22bfloat162_rn(make_float2(a.x, a.y));
            r[1] = __float22bfloat162_rn(make_float2(a.z, a.w));
            r[2] = __float22bfloat162_rn(make_float2(c.x, c.y));
            r[3] = __float22bfloat162_rn(make_float2(c.z, c.w));
            *(uint4*)(conv + base) = *(uint4*)r;
        }
    } else {
        const int isf = detect_fp32(x_drug);
        int i = (b - HB - CB) * 256 + t;          // 65536 total
        int p = i >> 15;
        int o = i & 32767;
        int j = o & 7, l = (o >> 3) & 63, nt = (o >> 9) & 7, kt = o >> 12;
        int k = kt * 32 + (l >> 4) * 8 + j;
        int n = (nt >> 2) * 64 + (l & 15) * 4 + (nt & 3);  // contiguous 4-col groups
        int kk = k & 127;
        const void* W;
        if (p == 0) W = (k < 128) ? W_dd : W_gd;
        else        W = (k < 128) ? W_dg : W_gg;
        float v = isf ? ((const float*)W)[kk * 128 + n]
                      : __bfloat162float(((const bf16*)W)[kk * 128 + n]);
        Bsw[i] = __float2bfloat16(v);
    }
}

// ---------------------------------------------------------------------------
// scanA: per-bucket column scan over 256 slices, COALESCED. Each block owns
// 64 columns; thread t = (quarter q, column c); two passes. Grid = 2*SAB.
// ---------------------------------------------------------------------------
__global__ __launch_bounds__(256) void scanA_kernel(
    int* __restrict__ tabD, int* __restrict__ tabS,
    int* __restrict__ btotD, int* __restrict__ btotS)
{
    __shared__ int qs[4][64];
    int t = threadIdx.x;
    int arr = blockIdx.x >= SAB;
    int blk = blockIdx.x - (arr ? SAB : 0);
    int* tab  = arr ? tabS : tabD;
    int* btot = arr ? btotS : btotD;
    int c = blk * 64 + (t & 63);
    int q = t >> 6;
    if (c >= NBKT) return;
    int sum = 0;
#pragma unroll 8
    for (int j = 0; j < 64; ++j) sum += tab[(q * 64 + j) * NBKT + c];
    qs[q][t & 63] = sum;
    __syncthreads();
    int off = 0;
    for (int qq = 0; qq < 4; ++qq) { if (qq < q) off += qs[qq][t & 63]; }
    if (q == 3) btot[c] = off + sum;
    int run = off;
#pragma unroll 8
    for (int j = 0; j < 64; ++j) {
        int idx = (q * 64 + j) * NBKT + c;
        int v = tab[idx];
        tab[idx] = run;
        run += v;
    }
}

// ---------------------------------------------------------------------------
// passB: partition edges into 256-id coarse buckets. Bucket bases computed
// in-block (redundant scan of btot). Per-block LDS cursors, no global
// atomics. Payloads: ED[pos] = (d&255)<<24 | packed_src ; SK[pos] = s&255.
// ---------------------------------------------------------------------------
__global__ __launch_bounds__(256) void passB_kernel(
    const int* __restrict__ src_dd, const int* __restrict__ dst_dd,
    const int* __restrict__ src_gd, const int* __restrict__ dst_gd,
    const int* __restrict__ src_dg, const int* __restrict__ dst_dg,
    const int* __restrict__ src_gg, const int* __restrict__ dst_gg,
    const int* __restrict__ tabD, const int* __restrict__ tabS,
    const int* __restrict__ btotD, const int* __restrict__ btotS,
    unsigned int* __restrict__ ED, unsigned char* __restrict__ SK)
{
    __shared__ int curD[NBKT], curS[NBKT];
    __shared__ int smD[256], smS[256];
    const int blk = blockIdx.x, t = threadIdx.x;
    int vD[5], vS[5]; int locD = 0, locS = 0;
#pragma unroll
    for (int j = 0; j < 5; ++j) {
        int idx = t * 5 + j;
        int xD = (idx < NBKT) ? btotD[idx] : 0;
        int xS = (idx < NBKT) ? btotS[idx] : 0;
        vD[j] = locD; locD += xD;
        vS[j] = locS; locS += xS;
    }
    smD[t] = locD; smS[t] = locS;
    __syncthreads();
    for (int off = 1; off < 256; off <<= 1) {
        int uD = (t >= off) ? smD[t - off] : 0;
        int uS = (t >= off) ? smS[t - off] : 0;
        __syncthreads();
        smD[t] += uD; smS[t] += uS;
        __syncthreads();
    }
    int baseD = smD[t] - locD, baseS = smS[t] - locS;
#pragma unroll
    for (int j = 0; j < 5; ++j) {
        int idx = t * 5 + j;
        if (idx < NBKT) {
            curD[idx] = baseD + vD[j] + tabD[blk * NBKT + idx];
            curS[idx] = baseS + vS[j] + tabS[blk * NBKT + idx];
        }
    }
    __syncthreads();
    ETYPE_SELECT(blk);
    for (int i = lo_ + t; i < lo_ + EPS; i += 256) {
        int s = sbase_ + sp_[i];
        int d = dbase_ + dp_[i];
        int pD = atomicAdd(&curD[d >> BSH], 1);
        ED[pD] = ((unsigned int)(d & 255) << 24) | (unsigned int)s;
        int pS = atomicAdd(&curS[s >> BSH], 1);
        SK[pS] = (unsigned char)(s & 255);
    }
}

// ---------------------------------------------------------------------------
// Block-prefix helper: lo = sum btot[0..b), hi = lo + btot[b]   (redundant)
// ---------------------------------------------------------------------------
__device__ __forceinline__ void bucket_range(
    const int* __restrict__ btot, int b, int t, int* lohi)
{
    __shared__ int red[4];
    int p = 0;
    for (int i = t; i < b; i += 256) p += btot[i];
#pragma unroll
    for (int off = 32; off; off >>= 1) p += __shfl_down(p, off, 64);
    if ((t & 63) == 0) red[t >> 6] = p;
    __syncthreads();
    if (t == 0) {
        int lo = red[0] + red[1] + red[2] + red[3];
        lohi[0] = lo;
        lohi[1] = lo + btot[b];
    }
    __syncthreads();
}

// ---------------------------------------------------------------------------
// passC: MERGED. Two block-ranges, independent:
//   [0,NBKT)        Cs: per-bucket out-degree counts from partitioned SK
//   [NBKT,2*NBKT)   Cd: CSR finalize — fine dst counts, in-LDS scan -> rp,
//                   reorder bucket edges into exact CSR order IN-PLACE over
//                   ED, storing raw packed src (deg looked up by the gather).
// ---------------------------------------------------------------------------
__global__ __launch_bounds__(256) void passC_kernel(
    unsigned int* __restrict__ ED, const unsigned char* __restrict__ SK,
    const int* __restrict__ btotD, const int* __restrict__ btotS,
    int* __restrict__ deg_out, int* __restrict__ rp)
{
    extern __shared__ unsigned int stage[];        // CAP entries (32 KiB)
    __shared__ int cnt[256];
    __shared__ int sm[256];
    __shared__ int cur[256];
    __shared__ int lohi[2];
    const int t = threadIdx.x;
    if (blockIdx.x < NBKT) {
        const int b = blockIdx.x;
        cnt[t] = 0;
        bucket_range(btotS, b, t, lohi);
        int lo = lohi[0], hi = lohi[1];
        for (int i = lo + t; i < hi; i += 256) atomicAdd(&cnt[SK[i]], 1);
        __syncthreads();
        deg_out[b * 256 + t] = cnt[t];
        return;
    }
    const int b = blockIdx.x - NBKT;
    cnt[t] = 0;
    bucket_range(btotD, b, t, lohi);
    int lo = lohi[0], hi = lohi[1];
    int n = hi - lo;
    for (int i = lo + t; i < hi; i += 256) atomicAdd(&cnt[ED[i] >> 24], 1);
    __syncthreads();
    int v = cnt[t];
    sm[t] = v;
    __syncthreads();
    for (int off = 1; off < 256; off <<= 1) {
        int u = (t >= off) ? sm[t - off] : 0;
        __syncthreads();
        sm[t] += u;
        __syncthreads();
    }
    int excl = sm[t] - v;
    int idx = b * 256 + t;
    if (idx < NTOT) rp[idx] = lo + excl;
    if (b == 0 && t == 0) rp[NTOT] = ETOT;
    cur[t] = excl;
    __syncthreads();
    for (int i = lo + t; i < hi; i += 256) {
        unsigned int e = ED[i];
        int pos = atomicAdd(&cur[e >> 24], 1);
        stage[pos] = e & 0xFFFFFF;     // raw packed src
    }
    __syncthreads();
    for (int i = t; i < n; i += 256) ED[lo + i] = stage[i];
}

// ---------------------------------------------------------------------------
// FUSED gather + GEMM + epilogue. Wave pair shares a 16-row A-tile (8 rows x
// 2 K-halves gathered per wave into LDS), then M=16,K=256 MFMA with an N=64
// split per wave, B direct from L2-resident Bsw.
// Gather: wave-wide edge preload — one coalesced load brings <=64 srcp
// entries + their rsqrt(deg) into lane registers; distribution to the four
// 16-lane groups uses __shfl (bpermute: divergent index is VALID, unlike
// readlane — the r6 bug). Inactive preload lanes hold (safe base, 0.0) so
// phantom edges read valid row 0 and contribute exactly 0 (no tail branch).
// ---------------------------------------------------------------------------
__device__ __forceinline__ void acc8(float* acc, uint4 raw, float nm)
{
    const __hip_bfloat162* p2 = (const __hip_bfloat162*)&raw;
#pragma unroll
    for (int j = 0; j < 4; ++j) {
        float2 f = __bfloat1622float2(p2[j]);
        acc[2 * j]     = fmaf(f.x, nm, acc[2 * j]);
        acc[2 * j + 1] = fmaf(f.y, nm, acc[2 * j + 1]);
    }
}

__global__ __launch_bounds__(256, 8) void gg_kernel(
    const void* __restrict__ x_drug, const void* __restrict__ x_gene,
    const bf16* __restrict__ conv,
    const unsigned int* __restrict__ srcp, const int* __restrict__ rp,
    const int* __restrict__ deg_out,
    const bf16* __restrict__ Bsw, const void* __restrict__ bias,
    void* __restrict__ out_)
{
    __shared__ bf16 Ast[2][16 * ALD];     // 16640 B
    __shared__ float ssx[2][2][4][4];     // [pair][wvh][grp][reg]
    const int isf = detect_fp32(x_drug);
    const bf16* xd = isf ? conv            : (const bf16*)x_drug;
    const bf16* xg = isf ? conv + XD_ELEMS : (const bf16*)x_gene;

    const int wv = threadIdx.x >> 6, lane = threadIdx.x & 63;
    const int pair = wv >> 1, wvh = wv & 1;
    const int phase = (blockIdx.x >= G0) ? 1 : 0;
    const int blk = phase ? blockIdx.x - G0 : blockIdx.x;
    const int rows = phase ? NG : ND;
    const int row_off = phase ? ND : 0;
    const int w0base = phase ? 2 * ND : 0;         // half0 packed-dst base
    const int w1base = phase ? 2 * ND + NG : ND;   // half1 packed-dst base
    const int s0base = phase ? ND + NG : 0;        // half0 packed-src base
    const int s1base = phase ? 2 * ND + NG : ND;   // half1 packed-src base
    const int r0 = blk * 32 + pair * 16;

    bf16* A = Ast[pair];
    const int g = lane >> 4;
    const int c = lane & 15;

    // x pointers pre-offset by packed-src base: index directly with s_packed
    const bf16* xh[2] = { xd - (size_t)s0base * 128,
                          xg - (size_t)s1base * 128 };
    const int wb[2] = { w0base, w1base };
    const unsigned int sb_h[2] = { (unsigned int)s0base, (unsigned int)s1base };

    // ---- gather phase: 8 rows x 2 halves per wave into the shared tile ----
    for (int rr = 0; rr < 8; ++rr) {
        int r = r0 + wvh * 8 + rr;
        int trow = wvh * 8 + rr;
#pragma unroll
        for (int h = 0; h < 2; ++h) {
            if (r >= rows) {
                if (g == 0) *(uint4*)(A + trow * ALD + h * 128 + c * 8) =
                    make_uint4(0, 0, 0, 0);
                continue;
            }
            int w = wb[h] + r;
            const bf16* x = xh[h];
            int beg = rp[w], end = rp[w + 1];
            int d = end - beg;
            float ndv = rsqrtf((float)max(d, 1));
            float acc[8] = {};
            for (int cb = 0; cb < d; cb += 64) {
                int cd = min(d - cb, 64);
                unsigned int sv = sb_h[h];   // safe pad: row 0 of this table
                float nv = 0.f;              // pad weight 0 -> contributes 0
                if (lane < cd) {
                    sv = srcp[beg + cb + lane];
                    nv = rsqrtf((float)max(deg_out[sv], 1));
                }
                for (int j = 0; j < cd; j += 8) {
                    unsigned int sa = (unsigned int)__shfl((int)sv, j + g, 64);
                    unsigned int sb2 = (unsigned int)__shfl((int)sv, j + 4 + g, 64);
                    float na = __shfl(nv, j + g, 64);
                    float nb = __shfl(nv, j + 4 + g, 64);
                    uint4 ra = *(const uint4*)(x + (size_t)sa * 128 + c * 8);
                    uint4 rb = *(const uint4*)(x + (size_t)sb2 * 128 + c * 8);
                    acc8(acc, ra, na);
                    acc8(acc, rb, nb);
                }
            }
#pragma unroll
            for (int j = 0; j < 8; ++j) {
                acc[j] += __shfl_xor(acc[j], 16, 64);
                acc[j] += __shfl_xor(acc[j], 32, 64);
            }
            if (g == 0) {
                __hip_bfloat162 o[4];
#pragma unroll
                for (int j = 0; j < 4; ++j)
                    o[j] = __float22bfloat162_rn(
                        make_float2(acc[2 * j] * ndv, acc[2 * j + 1] * ndv));
                *(uint4*)(A + trow * ALD + h * 128 + c * 8) = *(uint4*)o;
            }
        }
    }
    __syncthreads();

    // ---- MFMA phase: M=16, N=64 per wave (wvh picks nt-half), K=256 ----
    const bf16* Bp = Bsw + phase * 32768;
    f32x4 acc2[4];
#pragma unroll
    for (int nt = 0; nt < 4; ++nt) acc2[nt] = (f32x4){0.f, 0.f, 0.f, 0.f};

    const int arow = lane & 15;
    const int koff = (lane >> 4) * 8;
#pragma unroll
    for (int kt = 0; kt < 8; ++kt) {
        bf16x8 a = *(const bf16x8*)(A + arow * ALD + kt * 32 + koff);
#pragma unroll
        for (int nt = 0; nt < 4; ++nt) {
            int ntg = wvh * 4 + nt;
            bf16x8 b = *(const bf16x8*)(Bp + ((kt * 8 + ntg) * 64 + lane) * 8);
            acc2[nt] = __builtin_amdgcn_mfma_f32_16x16x32_bf16(a, b, acc2[nt], 0, 0, 0);
        }
    }

    // ---- epilogue: bias + ReLU, cross-wave L2-norm, contiguous stores ----
    // acc2[nt][reg] is col wvh*64 + ncol*4 + nt of row r0 + grp*4 + reg.
    const int ncol = lane & 15;
    const int grp = lane >> 4;
    float bv[4];
#pragma unroll
    for (int nt = 0; nt < 4; ++nt)
        bv[nt] = isf ? ((const float*)bias)[wvh * 64 + ncol * 4 + nt]
                     : __bfloat162float(((const bf16*)bias)[wvh * 64 + ncol * 4 + nt]);

    float h[4][4]; float ssp[4];
#pragma unroll
    for (int reg = 0; reg < 4; ++reg) {
        float ss = 0.f;
#pragma unroll
        for (int nt = 0; nt < 4; ++nt) {
            float v = acc2[nt][reg] + bv[nt];
            v = fmaxf(v, 0.f);
            h[reg][nt] = v;
            ss = fmaf(v, v, ss);
        }
        ss += __shfl_xor(ss, 1, 64);
        ss += __shfl_xor(ss, 2, 64);
        ss += __shfl_xor(ss, 4, 64);
        ss += __shfl_xor(ss, 8, 64);
        ssp[reg] = ss;
        if (ncol == 0) ssx[pair][wvh][grp][reg] = ss;
    }
    __syncthreads();
#pragma unroll
    for (int reg = 0; reg < 4; ++reg) {
        int row = r0 + grp * 4 + reg;
        float sst = ssp[reg] + ssx[pair][wvh ^ 1][grp][reg];
        float sc = 1.0f / fmaxf(sqrtf(sst), 1e-12f);
        if (row < rows) {
            size_t ob = (size_t)(row + row_off) * NF + wvh * 64 + ncol * 4;
            if (isf) {
                float* op = (float*)out_ + ob;
                *(float4*)op = make_float4(h[reg][0] * sc, h[reg][1] * sc,
                                           h[reg][2] * sc, h[reg][3] * sc);
            } else {
                bf16* op = (bf16*)out_ + ob;
                __hip_bfloat162 o[2];
                o[0] = __float22bfloat162_rn(make_float2(h[reg][0] * sc, h[reg][1] * sc));
                o[1] = __float22bfloat162_rn(make_float2(h[reg][2] * sc, h[reg][3] * sc));
                *(uint2*)op = *(uint2*)o;
            }
        }
    }
}

// ---------------------------------------------------------------------------
extern "C" void kernel_launch(void* const* d_in, const int* in_sizes, int n_in,
                              void* d_out, int out_size, void* d_ws, size_t ws_size,
                              hipStream_t stream)
{
    const void* x_drug = d_in[0];
    const void* x_gene = d_in[1];
    const void* W_dd   = d_in[2];
    const void* W_dg   = d_in[3];
    const void* W_gd   = d_in[4];
    const void* W_gg   = d_in[5];
    const void* h_bias = d_in[6];
    const int* src_dd = (const int*)d_in[7];
    const int* dst_dd = (const int*)d_in[8];
    const int* src_dg = (const int*)d_in[9];
    const int* dst_dg = (const int*)d_in[10];
    const int* src_gd = (const int*)d_in[11];
    const int* dst_gd = (const int*)d_in[12];
    const int* src_gg = (const int*)d_in[13];
    const int* dst_gg = (const int*)d_in[14];

    // ---- workspace layout ----
    bf16* Bsw  = (bf16*)d_ws;                 // [2][32768]
    bf16* conv = Bsw + 65536;                 // [XTOT] bf16 x copy
    int*  ib   = (int*)(conv + XTOT);
    int* tabD    = ib;                        // [256][1172] = 300032
    int* tabS    = ib + 300032;               // 300032 -> 600064
    int* btotD   = ib + 600064;               // 1172   -> 601236
    int* btotS   = ib + 601236;               // 1172   -> 602408
    int* deg_out = ib + 602408;               // 300032 -> 902440
    int* rp_all  = ib + 902440;               // 300001 -> 1202441
    unsigned int*  ED = (unsigned int*)(ib + 1202441);  // 2400000 -> 3602441
    unsigned char* SK = (unsigned char*)(ib + 3602441); // 2400000 B -> 4202441
                                              // end: ib + 4202441 ints

    size_t needed = 131072 + (size_t)XTOT * 2 + 4202441ull * 4;
    if (ws_size < needed) {
        hipMemsetAsync(d_out, 0, (size_t)out_size * 2, stream);
        return;
    }

    const int TB = 256;

    pre_kernel<<<HB + CB + PB, TB, 0, stream>>>(
        src_dd, dst_dd, src_gd, dst_gd, src_dg, dst_dg, src_gg, dst_gg,
        tabD, tabS, x_drug, x_gene, conv,
        W_dd, W_gd, W_dg, W_gg, Bsw);

    scanA_kernel<<<2 * SAB, TB, 0, stream>>>(tabD, tabS, btotD, btotS);

    passB_kernel<<<HB, TB, 0, stream>>>(
        src_dd, dst_dd, src_gd, dst_gd, src_dg, dst_dg, src_gg, dst_gg,
        tabD, tabS, btotD, btotS, ED, SK);

    passC_kernel<<<2 * NBKT, TB, CAP * sizeof(unsigned int), stream>>>(
        ED, SK, btotD, btotS, deg_out, rp_all);

    gg_kernel<<<G0 + G1, TB, 0, stream>>>(
        x_drug, x_gene, conv, ED, rp_all, deg_out, Bsw, h_bias, d_out);
}